// Round 1
// baseline (2301.602 us; speedup 1.0000x reference)
//
#include <hip/hip_runtime.h>

#define NODE 128
#define EDGE 64
#define FEAT 192      // NODE + EDGE
#define OUTC 128
#define NPD 125000
#define N_ATOMS_C 500000
#define ROWS 16
#define BN_EPS 1e-5f

// stats layout in d_ws: [0..127] sum -> mean, [128..255] sumsq -> rstd
__global__ void zero_stats_kernel(float* stats) {
    int t = threadIdx.x;
    if (t < 256) stats[t] = 0.f;
}

__global__ __launch_bounds__(256) void compute_x_kernel(
    const float* __restrict__ atom_repr, const float* __restrict__ bond_repr,
    const int* __restrict__ a1, const int* __restrict__ b1, const float* __restrict__ w1,
    const int* __restrict__ a2, const int* __restrict__ b2, const float* __restrict__ w2,
    const int* __restrict__ a3, const int* __restrict__ b3, const float* __restrict__ w3,
    const int* __restrict__ a4, const int* __restrict__ b4, const float* __restrict__ w4,
    const float* __restrict__ W_self, const float* __restrict__ bias,
    float* __restrict__ out, float* __restrict__ stats)
{
    const int seg = blockIdx.y;           // degree segment 0..3
    const int deg = seg + 1;
    const int* aidx; const int* bidx; const float* W;
    if (seg == 0)      { aidx = a1; bidx = b1; W = w1; }
    else if (seg == 1) { aidx = a2; bidx = b2; W = w2; }
    else if (seg == 2) { aidx = a3; bidx = b3; W = w3; }
    else               { aidx = a4; bidx = b4; W = w4; }

    __shared__ float s_self[ROWS][NODE];   // 8 KB
    __shared__ float s_feat[ROWS][FEAT];   // 12 KB  (a_sum | b_sum)
    __shared__ float s_sum[OUTC];
    __shared__ float s_sq[OUTC];

    const int tid = threadIdx.x;
    if (tid < OUTC) { s_sum[tid] = 0.f; s_sq[tid] = 0.f; }

    // ---------------- gather phase: 16 threads per row ----------------
    {
        const int r  = tid >> 4;                    // 0..15 row in block
        const int t  = tid & 15;                    // 0..15 lane in row
        const int r0 = blockIdx.x * ROWS + r;       // row within segment
        const bool valid = (r0 < NPD);

        int ai[4], bi[4];
        #pragma unroll
        for (int j = 0; j < 4; ++j) {
            bool on = valid && (j < deg);
            ai[j] = on ? aidx[r0 * deg + j] : 0;
            bi[j] = on ? bidx[r0 * deg + j] : 0;
        }

        const float4* ar = (const float4*)atom_repr;   // 32 float4 per atom row
        const float4* br = (const float4*)bond_repr;   // 16 float4 per bond row
        const int gi = seg * NPD + (r0 < NPD ? r0 : 0);

        // self + atom-neighbor sum: 32 float4 per row, this thread does c=t, t+16
        #pragma unroll
        for (int cc = 0; cc < 2; ++cc) {
            const int c = t + cc * 16;
            float4 self4 = make_float4(0.f, 0.f, 0.f, 0.f);
            float4 acc   = make_float4(0.f, 0.f, 0.f, 0.f);
            if (valid) {
                self4 = ar[(size_t)gi * 32 + c];
                #pragma unroll
                for (int j = 0; j < 4; ++j) {
                    if (j < deg) {
                        float4 v = ar[(size_t)ai[j] * 32 + c];
                        acc.x += v.x; acc.y += v.y; acc.z += v.z; acc.w += v.w;
                    }
                }
            }
            ((float4*)&s_self[r][0])[c] = self4;
            ((float4*)&s_feat[r][0])[c] = acc;
        }
        // bond-neighbor sum: 16 float4 per row, thread does c=t
        {
            const int c = t;
            float4 acc = make_float4(0.f, 0.f, 0.f, 0.f);
            if (valid) {
                #pragma unroll
                for (int j = 0; j < 4; ++j) {
                    if (j < deg) {
                        float4 v = br[(size_t)bi[j] * 16 + c];
                        acc.x += v.x; acc.y += v.y; acc.z += v.z; acc.w += v.w;
                    }
                }
            }
            ((float4*)&s_feat[r][NODE])[c] = acc;
        }
    }
    __syncthreads();

    // ---------------- matmul phase: thread = (channel o, row-half) ----------------
    const int o     = tid & 127;          // output channel
    const int rbase = (tid >> 7) * 8;     // 0 or 8: this thread's 8 rows

    float acc[8];
    {
        const float b0 = bias[o];
        #pragma unroll
        for (int rr = 0; rr < 8; ++rr) acc[rr] = b0;
    }

    // self part: K = 128
    {
        const float4* ws4 = (const float4*)(W_self + (size_t)o * NODE);  // 32 float4
        #pragma unroll 4
        for (int kk = 0; kk < 32; ++kk) {
            const float4 w = ws4[kk];
            #pragma unroll
            for (int rr = 0; rr < 8; ++rr) {
                const float4 s = ((const float4*)&s_self[rbase + rr][0])[kk];
                acc[rr] += w.x * s.x + w.y * s.y + w.z * s.z + w.w * s.w;
            }
        }
    }
    // neighbor part: K = 192
    {
        const float4* wd4 = (const float4*)(W + (size_t)o * FEAT);       // 48 float4
        #pragma unroll 4
        for (int kk = 0; kk < 48; ++kk) {
            const float4 w = wd4[kk];
            #pragma unroll
            for (int rr = 0; rr < 8; ++rr) {
                const float4 s = ((const float4*)&s_feat[rbase + rr][0])[kk];
                acc[rr] += w.x * s.x + w.y * s.y + w.z * s.z + w.w * s.w;
            }
        }
    }

    // store + per-block stat partials
    float lsum = 0.f, lsq = 0.f;
    const int rseg0 = blockIdx.x * ROWS + rbase;
    #pragma unroll
    for (int rr = 0; rr < 8; ++rr) {
        const int rloc = rseg0 + rr;
        if (rloc < NPD) {
            const float v = acc[rr];
            out[(size_t)(seg * NPD + rloc) * OUTC + o] = v;
            lsum += v;
            lsq  += v * v;
        }
    }
    atomicAdd(&s_sum[o], lsum);
    atomicAdd(&s_sq[o], lsq);
    __syncthreads();
    if (tid < OUTC) {
        atomicAdd(&stats[tid], s_sum[tid]);
        atomicAdd(&stats[OUTC + tid], s_sq[tid]);
    }
}

__global__ void finalize_stats_kernel(float* stats) {
    const int o = threadIdx.x;  // 128 threads
    const float inv_n = 1.0f / (float)N_ATOMS_C;
    const float mean = stats[o] * inv_n;
    const float var  = stats[OUTC + o] * inv_n - mean * mean;
    stats[o] = mean;
    stats[OUTC + o] = rsqrtf(var + BN_EPS);
}

__global__ __launch_bounds__(256) void bn_relu_kernel(float* __restrict__ x,
                                                      const float* __restrict__ stats) {
    const size_t e = (size_t)blockIdx.x * 256 + threadIdx.x;  // float4 index, 16M total
    const int c4 = (int)(e & 31);                             // float4 within channel dim
    const float4 m = ((const float4*)stats)[c4];
    const float4 s = ((const float4*)stats)[32 + c4];
    float4 v = ((float4*)x)[e];
    v.x = fmaxf((v.x - m.x) * s.x, 0.f);
    v.y = fmaxf((v.y - m.y) * s.y, 0.f);
    v.z = fmaxf((v.z - m.z) * s.z, 0.f);
    v.w = fmaxf((v.w - m.w) * s.w, 0.f);
    ((float4*)x)[e] = v;
}

extern "C" void kernel_launch(void* const* d_in, const int* in_sizes, int n_in,
                              void* d_out, int out_size, void* d_ws, size_t ws_size,
                              hipStream_t stream) {
    const float* atom_repr = (const float*)d_in[0];
    const float* bond_repr = (const float*)d_in[1];
    const int*   a1 = (const int*)d_in[2];
    const int*   b1 = (const int*)d_in[3];
    const float* w1 = (const float*)d_in[4];
    const int*   a2 = (const int*)d_in[5];
    const int*   b2 = (const int*)d_in[6];
    const float* w2 = (const float*)d_in[7];
    const int*   a3 = (const int*)d_in[8];
    const int*   b3 = (const int*)d_in[9];
    const float* w3 = (const float*)d_in[10];
    const int*   a4 = (const int*)d_in[11];
    const int*   b4 = (const int*)d_in[12];
    const float* w4 = (const float*)d_in[13];
    const float* W_self = (const float*)d_in[14];
    const float* bias   = (const float*)d_in[15];

    float* out   = (float*)d_out;
    float* stats = (float*)d_ws;   // 256 floats

    zero_stats_kernel<<<1, 256, 0, stream>>>(stats);

    dim3 grid((NPD + ROWS - 1) / ROWS, 4);   // 7813 x 4 blocks
    compute_x_kernel<<<grid, 256, 0, stream>>>(
        atom_repr, bond_repr,
        a1, b1, w1, a2, b2, w2, a3, b3, w3, a4, b4, w4,
        W_self, bias, out, stats);

    finalize_stats_kernel<<<1, 128, 0, stream>>>(stats);

    // 500000*128 floats = 16M float4
    bn_relu_kernel<<<(N_ATOMS_C * (OUTC / 4)) / 256, 256, 0, stream>>>(out, stats);
}

// Round 2
// 909.883 us; speedup vs baseline: 2.5296x; 2.5296x over previous
//
#include <hip/hip_runtime.h>

#define NODE 128
#define EDGE 64
#define OUTC 128
#define KTOT 320          // NODE + NODE + EDGE  (self | atom-sum | bond-sum)
#define NPD 125000
#define N_ATOMS_C 500000
#define BROWS 32          // rows per batch (2 MFMA m-tiles)
#define NB 4              // batches per block
#define NBLK 977          // ceil(125000 / (32*4))
#define LDST 328          // padded LDS row stride (bf16 units): 656 B -> 2-way-free banks
#define BN_EPS 1e-5f

typedef short bf16x8 __attribute__((ext_vector_type(8)));
typedef float floatx4 __attribute__((ext_vector_type(4)));

__device__ __forceinline__ unsigned short f2bf(float f) {
    unsigned u = __float_as_uint(f);
    u += 0x7fffu + ((u >> 16) & 1u);     // round-to-nearest-even
    return (unsigned short)(u >> 16);
}
__device__ __forceinline__ unsigned pack2(float a, float b) {
    return (unsigned)f2bf(a) | ((unsigned)f2bf(b) << 16);
}

// ws layout: [0..255] f32 stats (sum | sumsq -> mean | rstd), then bf16 Wcat[4][128][320]
__global__ __launch_bounds__(256) void pack_weights_kernel(
    const float* __restrict__ w1, const float* __restrict__ w2,
    const float* __restrict__ w3, const float* __restrict__ w4,
    const float* __restrict__ W_self, float* __restrict__ stats,
    unsigned short* __restrict__ Wcat)
{
    if (blockIdx.x == 0 && threadIdx.x < 256) stats[threadIdx.x] = 0.f;
    const int idx = blockIdx.x * 256 + threadIdx.x;      // 4*128*320 = 163840
    if (idx >= 4 * OUTC * KTOT) return;
    const int d   = idx / (OUTC * KTOT);
    const int rem = idx % (OUTC * KTOT);
    const int n = rem / KTOT, k = rem % KTOT;
    const float* wd = (d == 0) ? w1 : (d == 1) ? w2 : (d == 2) ? w3 : w4;
    const float v = (k < NODE) ? W_self[n * NODE + k]
                               : wd[n * (NODE + EDGE) + (k - NODE)];
    Wcat[idx] = f2bf(v);
}

__global__ __launch_bounds__(256) void compute_x_kernel(
    const float* __restrict__ atom_repr, const float* __restrict__ bond_repr,
    const int* __restrict__ a1, const int* __restrict__ b1,
    const int* __restrict__ a2, const int* __restrict__ b2,
    const int* __restrict__ a3, const int* __restrict__ b3,
    const int* __restrict__ a4, const int* __restrict__ b4,
    const unsigned short* __restrict__ Wcat, const float* __restrict__ bias,
    float* __restrict__ out, float* __restrict__ stats)
{
    const int seg = blockIdx.y;
    const int deg = seg + 1;
    const int* aidx = (seg == 0) ? a1 : (seg == 1) ? a2 : (seg == 2) ? a3 : a4;
    const int* bidx = (seg == 0) ? b1 : (seg == 1) ? b2 : (seg == 2) ? b3 : b4;

    __shared__ unsigned short s_feat[BROWS][LDST];   // ~21 KB
    __shared__ float s_sum[OUTC], s_sq[OUTC];

    const int tid = threadIdx.x;
    if (tid < OUTC) { s_sum[tid] = 0.f; s_sq[tid] = 0.f; }

    const int w    = tid >> 6;      // wave 0..3 -> n-chunk of 32
    const int lane = tid & 63;
    const int quad = lane >> 4;
    const int lrow = lane & 15;

    // ---- B slab in registers: 2 n-tiles x 10 k-steps, 16 B each = 80 VGPRs ----
    bf16x8 breg[2][10];
    {
        const unsigned short* Wc = Wcat + (size_t)seg * OUTC * KTOT;
        #pragma unroll
        for (int nt = 0; nt < 2; ++nt) {
            const int n = w * 32 + nt * 16 + lrow;
            #pragma unroll
            for (int ks = 0; ks < 10; ++ks) {
                const int k0 = quad * 8 + ks * 32;
                breg[nt][ks] = *reinterpret_cast<const bf16x8*>(Wc + n * KTOT + k0);
            }
        }
    }
    float bias_v[2];
    bias_v[0] = bias[w * 32 + lrow];
    bias_v[1] = bias[w * 32 + 16 + lrow];

    float lsum[2] = {0.f, 0.f}, lsq[2] = {0.f, 0.f};

    const int gr = tid >> 3;    // gather: 8 threads per row, 32 rows
    const int gt = tid & 7;

    for (int b = 0; b < NB; ++b) {
        const int base = (blockIdx.x * NB + b) * BROWS;
        if (base >= NPD) break;              // block-uniform

        // ---------------- gather -> bf16 LDS ----------------
        {
            const int r0 = base + gr;
            const bool valid = (r0 < NPD);
            int ai[4], bi[4];
            #pragma unroll
            for (int j = 0; j < 4; ++j) {
                const bool on = valid && (j < deg);
                ai[j] = on ? aidx[r0 * deg + j] : 0;
                bi[j] = on ? bidx[r0 * deg + j] : 0;
            }
            const float4* ar = (const float4*)atom_repr;
            const float4* br = (const float4*)bond_repr;
            const size_t gi = (size_t)(seg * NPD) + (valid ? r0 : 0);

            #pragma unroll
            for (int h = 0; h < 2; ++h) {
                const int k0 = h * 64 + gt * 8;       // 8 floats -> 8 bf16
                // self
                float4 s0 = make_float4(0, 0, 0, 0), s1 = make_float4(0, 0, 0, 0);
                if (valid) {
                    s0 = ar[gi * 32 + (k0 >> 2)];
                    s1 = ar[gi * 32 + (k0 >> 2) + 1];
                }
                uint4 p;
                p.x = pack2(s0.x, s0.y); p.y = pack2(s0.z, s0.w);
                p.z = pack2(s1.x, s1.y); p.w = pack2(s1.z, s1.w);
                *reinterpret_cast<uint4*>(&s_feat[gr][k0]) = p;
                // atom-neighbor sum
                float4 u0 = make_float4(0, 0, 0, 0), u1 = make_float4(0, 0, 0, 0);
                #pragma unroll
                for (int j = 0; j < 4; ++j) {
                    if (j < deg && valid) {
                        const float4 v0 = ar[(size_t)ai[j] * 32 + (k0 >> 2)];
                        const float4 v1 = ar[(size_t)ai[j] * 32 + (k0 >> 2) + 1];
                        u0.x += v0.x; u0.y += v0.y; u0.z += v0.z; u0.w += v0.w;
                        u1.x += v1.x; u1.y += v1.y; u1.z += v1.z; u1.w += v1.w;
                    }
                }
                p.x = pack2(u0.x, u0.y); p.y = pack2(u0.z, u0.w);
                p.z = pack2(u1.x, u1.y); p.w = pack2(u1.z, u1.w);
                *reinterpret_cast<uint4*>(&s_feat[gr][NODE + k0]) = p;
            }
            // bond-neighbor sum (64 floats per row)
            {
                const int k0 = gt * 8;
                float4 u0 = make_float4(0, 0, 0, 0), u1 = make_float4(0, 0, 0, 0);
                #pragma unroll
                for (int j = 0; j < 4; ++j) {
                    if (j < deg && valid) {
                        const float4 v0 = br[(size_t)bi[j] * 16 + (k0 >> 2)];
                        const float4 v1 = br[(size_t)bi[j] * 16 + (k0 >> 2) + 1];
                        u0.x += v0.x; u0.y += v0.y; u0.z += v0.z; u0.w += v0.w;
                        u1.x += v1.x; u1.y += v1.y; u1.z += v1.z; u1.w += v1.w;
                    }
                }
                uint4 p;
                p.x = pack2(u0.x, u0.y); p.y = pack2(u0.z, u0.w);
                p.z = pack2(u1.x, u1.y); p.w = pack2(u1.z, u1.w);
                *reinterpret_cast<uint4*>(&s_feat[gr][2 * NODE + k0]) = p;
            }
        }
        __syncthreads();

        // ---------------- MFMA: [32 x 320] x [320 x 128] ----------------
        floatx4 acc[2][2];
        #pragma unroll
        for (int mt = 0; mt < 2; ++mt)
            #pragma unroll
            for (int nt = 0; nt < 2; ++nt) {
                acc[mt][nt][0] = bias_v[nt]; acc[mt][nt][1] = bias_v[nt];
                acc[mt][nt][2] = bias_v[nt]; acc[mt][nt][3] = bias_v[nt];
            }
        #pragma unroll
        for (int ks = 0; ks < 10; ++ks) {
            bf16x8 af[2];
            af[0] = *reinterpret_cast<const bf16x8*>(&s_feat[lrow][quad * 8 + ks * 32]);
            af[1] = *reinterpret_cast<const bf16x8*>(&s_feat[16 + lrow][quad * 8 + ks * 32]);
            #pragma unroll
            for (int mt = 0; mt < 2; ++mt)
                #pragma unroll
                for (int nt = 0; nt < 2; ++nt)
                    acc[mt][nt] = __builtin_amdgcn_mfma_f32_16x16x32_bf16(
                        af[mt], breg[nt][ks], acc[mt][nt], 0, 0, 0);
        }

        // ---------------- store + stats ----------------
        #pragma unroll
        for (int mt = 0; mt < 2; ++mt) {
            #pragma unroll
            for (int nt = 0; nt < 2; ++nt) {
                const int n = w * 32 + nt * 16 + lrow;
                #pragma unroll
                for (int r = 0; r < 4; ++r) {
                    const int m = mt * 16 + quad * 4 + r;
                    const int row = base + m;
                    if (row < NPD) {
                        const float v = acc[mt][nt][r];
                        out[(size_t)(seg * NPD + row) * OUTC + n] = v;
                        lsum[nt] += v; lsq[nt] += v * v;
                    }
                }
            }
        }
        __syncthreads();   // protect s_feat for next batch
    }

    atomicAdd(&s_sum[w * 32 + lrow], lsum[0]);
    atomicAdd(&s_sq [w * 32 + lrow], lsq[0]);
    atomicAdd(&s_sum[w * 32 + 16 + lrow], lsum[1]);
    atomicAdd(&s_sq [w * 32 + 16 + lrow], lsq[1]);
    __syncthreads();
    if (tid < OUTC) {
        atomicAdd(&stats[tid], s_sum[tid]);
        atomicAdd(&stats[OUTC + tid], s_sq[tid]);
    }
}

__global__ void finalize_stats_kernel(float* stats) {
    const int o = threadIdx.x;  // 128
    const float inv_n = 1.0f / (float)N_ATOMS_C;
    const float mean = stats[o] * inv_n;
    const float var  = stats[OUTC + o] * inv_n - mean * mean;
    stats[o] = mean;
    stats[OUTC + o] = rsqrtf(var + BN_EPS);
}

__global__ __launch_bounds__(256) void bn_relu_kernel(float* __restrict__ x,
                                                      const float* __restrict__ stats) {
    const size_t e = (size_t)blockIdx.x * 256 + threadIdx.x;  // float4 index
    const int c4 = (int)(e & 31);
    const float4 m = ((const float4*)stats)[c4];
    const float4 s = ((const float4*)stats)[32 + c4];
    float4 v = ((float4*)x)[e];
    v.x = fmaxf((v.x - m.x) * s.x, 0.f);
    v.y = fmaxf((v.y - m.y) * s.y, 0.f);
    v.z = fmaxf((v.z - m.z) * s.z, 0.f);
    v.w = fmaxf((v.w - m.w) * s.w, 0.f);
    ((float4*)x)[e] = v;
}

extern "C" void kernel_launch(void* const* d_in, const int* in_sizes, int n_in,
                              void* d_out, int out_size, void* d_ws, size_t ws_size,
                              hipStream_t stream) {
    const float* atom_repr = (const float*)d_in[0];
    const float* bond_repr = (const float*)d_in[1];
    const int*   a1 = (const int*)d_in[2];
    const int*   b1 = (const int*)d_in[3];
    const float* w1 = (const float*)d_in[4];
    const int*   a2 = (const int*)d_in[5];
    const int*   b2 = (const int*)d_in[6];
    const float* w2 = (const float*)d_in[7];
    const int*   a3 = (const int*)d_in[8];
    const int*   b3 = (const int*)d_in[9];
    const float* w3 = (const float*)d_in[10];
    const int*   a4 = (const int*)d_in[11];
    const int*   b4 = (const int*)d_in[12];
    const float* w4 = (const float*)d_in[13];
    const float* W_self = (const float*)d_in[14];
    const float* bias   = (const float*)d_in[15];

    float* out   = (float*)d_out;
    float* stats = (float*)d_ws;                                    // 256 f32
    unsigned short* Wcat = (unsigned short*)((char*)d_ws + 1024);   // bf16[4][128][320]

    pack_weights_kernel<<<(4 * OUTC * KTOT + 255) / 256, 256, 0, stream>>>(
        w1, w2, w3, w4, W_self, stats, Wcat);

    dim3 grid(NBLK, 4);
    compute_x_kernel<<<grid, 256, 0, stream>>>(
        atom_repr, bond_repr, a1, b1, a2, b2, a3, b3, a4, b4,
        Wcat, bias, out, stats);

    finalize_stats_kernel<<<1, 128, 0, stream>>>(stats);

    bn_relu_kernel<<<(N_ATOMS_C * (OUTC / 4)) / 256, 256, 0, stream>>>(out, stats);
}